// Round 9
// baseline (101.868 us; speedup 1.0000x reference)
//
#include <hip/hip_runtime.h>

#define N_NODES 100000
#define N_EDGES 1600000
#define HIDDEN 256

#define BSH 7                    // bucket = dst >> 7
#define BNODES 128               // nodes per bucket
#define NB 782                   // ceil(100000 / 128)
#define NPB 256                  // place blocks
#define EPB 6250                 // edges per place block (256*6250 = 1.6M exact)
#define SLOTS 32                 // slots per (bucket, place-block): mean 8, P(ovf)~4e-11

// rec layout: [bucket][pblock][slot], 8B records {src|dstloc<<17, w}
// cnt layout: [pblock][bucket]  — fully overwritten by k_place, no init needed

// ---- KP: single-pass place, 1024 threads/block ----
__global__ __launch_bounds__(1024) void k_place(
        const int* __restrict__ ei, const float* __restrict__ ew,
        int* __restrict__ cnt, uint2* __restrict__ rec) {
    __shared__ int cursor[NB];
    const int tid = threadIdx.x, bid = blockIdx.x;
    for (int i = tid; i < NB; i += 1024) cursor[i] = 0;
    __syncthreads();
    const int e0 = bid * EPB, e1 = e0 + EPB;
    for (int e = e0 + tid; e < e1; e += 1024) {
        int d = ei[N_EDGES + e];
        int s = ei[e];
        float wv = ew[e];
        int bk = ((unsigned)d) >> BSH;
        int pos = atomicAdd(&cursor[bk], 1);          // block-local LDS cursor
        if (pos < SLOTS)                              // ~4e-11 per pair
            rec[((size_t)bk * NPB + bid) * SLOTS + pos] =
                make_uint2((unsigned)s | ((unsigned)(d & (BNODES - 1)) << 17),
                           __float_as_uint(wv));
    }
    __syncthreads();
    for (int i = tid; i < NB; i += 1024)
        cnt[bid * NB + i] = min(cursor[i], SLOTS);    // covers ALL entries
}

// ---- KDZ: per bucket — fold W12 (L2), z = x@W12 for own 128 nodes,
//           deg from records, write dinv + zn = dinv*z ----
__global__ __launch_bounds__(256) void k_degz(
        const float* __restrict__ x,
        const float* __restrict__ W1, const float* __restrict__ W2,
        const uint2* __restrict__ rec, const int* __restrict__ cnt,
        float* __restrict__ dinv, float2* __restrict__ zn) {
    __shared__ float w12[HIDDEN * 2];
    __shared__ float zloc[BNODES][2];
    __shared__ float acc[BNODES];
    __shared__ int csh[NPB];
    const int tid = threadIdx.x, b = blockIdx.x;

    // W12 fold: thread h computes row h of W1@W2 (reads L2-resident W1)
    {
        const float4* w1r = (const float4*)(W1 + (size_t)tid * 128);
        float a0 = 0.f, a1 = 0.f;
#pragma unroll 8
        for (int k4 = 0; k4 < 32; ++k4) {
            float4 v = w1r[k4];
            a0 += v.x * W2[8 * k4 + 0]; a1 += v.x * W2[8 * k4 + 1];
            a0 += v.y * W2[8 * k4 + 2]; a1 += v.y * W2[8 * k4 + 3];
            a0 += v.z * W2[8 * k4 + 4]; a1 += v.z * W2[8 * k4 + 5];
            a0 += v.w * W2[8 * k4 + 6]; a1 += v.w * W2[8 * k4 + 7];
        }
        w12[2 * tid] = a0; w12[2 * tid + 1] = a1;
    }
    for (int i = tid; i < BNODES; i += 256) acc[i] = 1.0f;   // self-loop w=1
    csh[tid] = cnt[tid * NB + b];
    __syncthreads();

    // z for this bucket's 128 nodes: 4 waves x 32 nodes each
    const int lane = tid & 63, wv = tid >> 6;
    const float2 wa = ((const float2*)w12)[lane * 4 + 0];
    const float2 wb = ((const float2*)w12)[lane * 4 + 1];
    const float2 wc = ((const float2*)w12)[lane * 4 + 2];
    const float2 wd = ((const float2*)w12)[lane * 4 + 3];
    const int base = b * BNODES;
#pragma unroll 4
    for (int k = 0; k < 32; ++k) {
        const int nl = wv * 32 + k;
        const int node = base + nl;                  // wave-uniform guard
        if (node < N_NODES) {
            float4 xv = *(const float4*)(x + (size_t)node * HIDDEN + lane * 4);
            float a0 = xv.x * wa.x + xv.y * wb.x + xv.z * wc.x + xv.w * wd.x;
            float a1 = xv.x * wa.y + xv.y * wb.y + xv.z * wc.y + xv.w * wd.y;
#pragma unroll
            for (int m = 32; m >= 1; m >>= 1) {
                a0 += __shfl_xor(a0, m, 64);
                a1 += __shfl_xor(a1, m, 64);
            }
            if (lane == 0) { zloc[nl][0] = a0; zloc[nl][1] = a1; }
        }
    }

    // deg from records (interleaves with z's memory traffic)
    const uint2* r = rec + (size_t)b * NPB * SLOTS;
    for (int idx = tid; idx < NPB * SLOTS; idx += 256) {
        int j = idx >> 5, s2 = idx & (SLOTS - 1);
        if (s2 < csh[j]) {
            uint2 q = r[idx];
            atomicAdd(&acc[q.x >> 17], __uint_as_float(q.y));
        }
    }
    __syncthreads();

    for (int i = tid; i < BNODES; i += 256) {
        int node = base + i;
        if (node < N_NODES) {
            float di = rsqrtf(acc[i]);               // deg >= 1 always
            dinv[node] = di;
            zn[node] = make_float2(di * zloc[i][0], di * zloc[i][1]);
        }
    }
}

// ---- KC: gather zn[src]*w per bucket; flush fuses self-loop + bias ----
__global__ __launch_bounds__(256) void k_gather(
        const uint2* __restrict__ rec, const int* __restrict__ cnt,
        const float* __restrict__ dinv, const float2* __restrict__ zn,
        const float* __restrict__ b1, const float* __restrict__ W2,
        const float* __restrict__ b2, float2* __restrict__ out) {
    __shared__ float ax[BNODES], ay[BNODES];
    __shared__ int csh[NPB];
    __shared__ float cv[2];
    const int tid = threadIdx.x, b = blockIdx.x;
    for (int i = tid; i < BNODES; i += 256) { ax[i] = 0.f; ay[i] = 0.f; }
    csh[tid] = cnt[tid * NB + b];
    if (tid < 2) {                                    // cvec = b1@W2 + b2 (tiny)
        float acc = b2[tid];
#pragma unroll 8
        for (int k = 0; k < 128; ++k) acc += b1[k] * W2[2 * k + tid];
        cv[tid] = acc;
    }
    __syncthreads();
    const uint2* r = rec + (size_t)b * NPB * SLOTS;
    for (int idx = tid; idx < NPB * SLOTS; idx += 256) {
        int j = idx >> 5, s2 = idx & (SLOTS - 1);
        if (s2 < csh[j]) {
            uint2 q = r[idx];
            float w = __uint_as_float(q.y);
            float2 s = zn[q.x & 0x1FFFFu];
            int dl = (int)(q.x >> 17);
            atomicAdd(&ax[dl], w * s.x);
            atomicAdd(&ay[dl], w * s.y);
        }
    }
    __syncthreads();
    const float c0 = cv[0], c1 = cv[1];
    for (int i2 = tid; i2 < BNODES; i2 += 256) {
        int node = b * BNODES + i2;
        if (node < N_NODES) {
            float di = dinv[node];
            float2 s = zn[node];
            out[node] = make_float2(di * ax[i2] + di * s.x + c0,
                                    di * ay[i2] + di * s.y + c1);
        }
    }
}

extern "C" void kernel_launch(void* const* d_in, const int* in_sizes, int n_in,
                              void* d_out, int out_size, void* d_ws, size_t ws_size,
                              hipStream_t stream) {
    const float* x  = (const float*)d_in[0];
    const int*   ei = (const int*)d_in[1];
    const float* ew = (const float*)d_in[2];
    const float* W1 = (const float*)d_in[3];
    const float* b1 = (const float*)d_in[4];
    const float* W2 = (const float*)d_in[5];
    const float* b2 = (const float*)d_in[6];
    float2* out = (float2*)d_out;

    char* ws = (char*)d_ws;
    uint2*  rec  = (uint2*)ws;           size_t off = (size_t)NB * NPB * SLOTS * 8;  // 51,249,152
    int*    cnt  = (int*)(ws + off);     off += (size_t)NPB * NB * 4;                // 800,768
    float*  dinv = (float*)(ws + off);   off += (size_t)N_NODES * 4;
    float2* zn   = (float2*)(ws + off);  off += (size_t)N_NODES * 8;

    k_place <<<NPB, 1024, 0, stream>>>(ei, ew, cnt, rec);
    k_degz  <<<NB, 256, 0, stream>>>(x, W1, W2, rec, cnt, dinv, zn);
    k_gather<<<NB, 256, 0, stream>>>(rec, cnt, dinv, zn, b1, W2, b2, out);
}

// Round 10
// 78.654 us; speedup vs baseline: 1.2951x; 1.2951x over previous
//
#include <hip/hip_runtime.h>

#define N_NODES 100000
#define N_EDGES 1600000
#define HIDDEN 256

#define BSH 7                    // bucket = dst >> 7
#define BNODES 128               // nodes per bucket
#define NB 782                   // ceil(100000 / 128)
#define NPB 256                  // place blocks == sub-chunks per bucket == consumer block size
#define EPB 6250                 // edges per place block (256*6250 = 1.6M exact)
#define SLOTS 32                 // slots per (bucket, pblock): mean 8, P(ovf)~4e-13/pair
#define NZB 12500                // z blocks: 4 waves x 2 nodes = 8 nodes/block, exact cover

// rec layout: [bucket][pblock][slot], 8B records {src(17b) | dstloc(7b)<<17, w}
// cnt layout: [bucket][pblock]  -> consumers read coalesced; fully overwritten each call

// ---- K1: place (blocks 0..255) + W12/cvec fold (block 256) ----
__global__ __launch_bounds__(1024) void k_place(
        const int* __restrict__ ei, const float* __restrict__ ew,
        const float* __restrict__ W1, const float* __restrict__ b1,
        const float* __restrict__ W2, const float* __restrict__ b2,
        int* __restrict__ cnt, uint2* __restrict__ rec,
        float* __restrict__ W12, float* __restrict__ cvec) {
    const int tid = threadIdx.x, bid = blockIdx.x;
    if (bid == NPB) {                                 // ---- fold block ----
        if (tid < HIDDEN) {
            const float4* w1r = (const float4*)(W1 + (size_t)tid * 128);
            float a0 = 0.f, a1 = 0.f;
#pragma unroll 8
            for (int k4 = 0; k4 < 32; ++k4) {
                float4 v = w1r[k4];
                a0 += v.x * W2[8 * k4 + 0]; a1 += v.x * W2[8 * k4 + 1];
                a0 += v.y * W2[8 * k4 + 2]; a1 += v.y * W2[8 * k4 + 3];
                a0 += v.z * W2[8 * k4 + 4]; a1 += v.z * W2[8 * k4 + 5];
                a0 += v.w * W2[8 * k4 + 6]; a1 += v.w * W2[8 * k4 + 7];
            }
            W12[2 * tid] = a0; W12[2 * tid + 1] = a1;
            if (tid < 2) {
                float acc = b2[tid];
                for (int k = 0; k < 128; ++k) acc += b1[k] * W2[2 * k + tid];
                cvec[tid] = acc;
            }
        }
        return;
    }
    __shared__ int cursor[NB];
    for (int i = tid; i < NB; i += 1024) cursor[i] = 0;
    __syncthreads();
    const int e0 = bid * EPB, e1 = e0 + EPB;
    for (int e = e0 + tid; e < e1; e += 1024) {
        int d = ei[N_EDGES + e];
        int s = ei[e];
        float wv = ew[e];
        int bk = ((unsigned)d) >> BSH;
        int pos = atomicAdd(&cursor[bk], 1);          // block-local LDS cursor
        if (pos < SLOTS)                              // ~4e-13 per pair
            rec[((size_t)bk * NPB + bid) * SLOTS + pos] =
                make_uint2((unsigned)s | ((unsigned)(d & (BNODES - 1)) << 17),
                           __float_as_uint(wv));
    }
    __syncthreads();
    for (int i = tid; i < NB; i += 1024)
        cnt[(size_t)i * NPB + bid] = min(cursor[i], SLOTS);   // covers ALL entries
}

// ---- K2: z = x@W12, 2 nodes per wave (ILP=2), exact cover ----
__global__ __launch_bounds__(256) void k_z(
        const float* __restrict__ x, const float* __restrict__ W12,
        float* __restrict__ z) {
    const int tid = threadIdx.x, lane = tid & 63;
    const float2 w0 = ((const float2*)W12)[lane * 4 + 0];
    const float2 w1 = ((const float2*)W12)[lane * 4 + 1];
    const float2 w2 = ((const float2*)W12)[lane * 4 + 2];
    const float2 w3 = ((const float2*)W12)[lane * 4 + 3];
    const int n0 = (blockIdx.x * 4 + (tid >> 6)) * 2;     // two consecutive nodes
    const float4 xa = *(const float4*)(x + (size_t)n0 * HIDDEN + lane * 4);
    const float4 xb = *(const float4*)(x + (size_t)(n0 + 1) * HIDDEN + lane * 4);
    float a0 = xa.x * w0.x + xa.y * w1.x + xa.z * w2.x + xa.w * w3.x;
    float a1 = xa.x * w0.y + xa.y * w1.y + xa.z * w2.y + xa.w * w3.y;
    float c0 = xb.x * w0.x + xb.y * w1.x + xb.z * w2.x + xb.w * w3.x;
    float c1 = xb.x * w0.y + xb.y * w1.y + xb.z * w2.y + xb.w * w3.y;
#pragma unroll
    for (int m = 32; m >= 1; m >>= 1) {                   // two independent chains
        a0 += __shfl_xor(a0, m, 64);
        a1 += __shfl_xor(a1, m, 64);
        c0 += __shfl_xor(c0, m, 64);
        c1 += __shfl_xor(c1, m, 64);
    }
    if (lane == 0) *(float4*)(z + 2 * n0) = make_float4(a0, a1, c0, c1);
}

// ---- K3: deg per bucket, one thread per sub-chunk -> dinv, zn = dinv*z ----
__global__ __launch_bounds__(256) void k_deg(
        const uint2* __restrict__ rec, const int* __restrict__ cnt,
        const float* __restrict__ z, float* __restrict__ dinv,
        float2* __restrict__ zn) {
    __shared__ float acc[BNODES];
    const int tid = threadIdx.x, b = blockIdx.x;
    if (tid < BNODES) acc[tid] = 1.0f;                    // self-loop w=1
    __syncthreads();
    const int n = cnt[(size_t)b * NPB + tid];             // coalesced
    const uint2* r = rec + ((size_t)b * NPB + tid) * SLOTS;
    for (int i = 0; i < n; ++i) {                         // ~8 iters, own 64B lines
        uint2 q = r[i];
        atomicAdd(&acc[q.x >> 17], __uint_as_float(q.y));
    }
    __syncthreads();
    if (tid < BNODES) {
        int node = b * BNODES + tid;
        if (node < N_NODES) {
            float di = rsqrtf(acc[tid]);                  // deg >= 1 always
            dinv[node] = di;
            float2 zv = ((const float2*)z)[node];
            zn[node] = make_float2(di * zv.x, di * zv.y);
        }
    }
}

// ---- K4: gather, one thread per sub-chunk; flush fuses self-loop + bias ----
__global__ __launch_bounds__(256) void k_gather(
        const uint2* __restrict__ rec, const int* __restrict__ cnt,
        const float* __restrict__ dinv, const float2* __restrict__ zn,
        const float* __restrict__ cvec, float2* __restrict__ out) {
    __shared__ float ax[BNODES], ay[BNODES];
    const int tid = threadIdx.x, b = blockIdx.x;
    if (tid < BNODES) { ax[tid] = 0.f; ay[tid] = 0.f; }
    __syncthreads();
    const int n = cnt[(size_t)b * NPB + tid];             // coalesced
    const uint2* r = rec + ((size_t)b * NPB + tid) * SLOTS;
    for (int i = 0; i < n; ++i) {
        uint2 q = r[i];
        float w = __uint_as_float(q.y);
        float2 s = zn[q.x & 0x1FFFFu];
        int dl = (int)(q.x >> 17);
        atomicAdd(&ax[dl], w * s.x);
        atomicAdd(&ay[dl], w * s.y);
    }
    __syncthreads();
    if (tid < BNODES) {
        int node = b * BNODES + tid;
        if (node < N_NODES) {
            float di = dinv[node];
            float2 s = zn[node];                          // s = dinv*z -> di*s = self-loop
            out[node] = make_float2(di * ax[tid] + di * s.x + cvec[0],
                                    di * ay[tid] + di * s.y + cvec[1]);
        }
    }
}

extern "C" void kernel_launch(void* const* d_in, const int* in_sizes, int n_in,
                              void* d_out, int out_size, void* d_ws, size_t ws_size,
                              hipStream_t stream) {
    const float* x  = (const float*)d_in[0];
    const int*   ei = (const int*)d_in[1];
    const float* ew = (const float*)d_in[2];
    const float* W1 = (const float*)d_in[3];
    const float* b1 = (const float*)d_in[4];
    const float* W2 = (const float*)d_in[5];
    const float* b2 = (const float*)d_in[6];
    float2* out = (float2*)d_out;

    char* ws = (char*)d_ws;
    uint2*  rec  = (uint2*)ws;           size_t off = (size_t)NB * NPB * SLOTS * 8;  // 51,249,152
    int*    cnt  = (int*)(ws + off);     off += (size_t)NB * NPB * 4;                // 800,768
    float*  dinv = (float*)(ws + off);   off += (size_t)N_NODES * 4;
    float*  z    = (float*)(ws + off);   off += (size_t)N_NODES * 8;
    float2* zn   = (float2*)(ws + off);  off += (size_t)N_NODES * 8;
    float*  W12  = (float*)(ws + off);   off += HIDDEN * 2 * 4;
    float*  cvec = (float*)(ws + off);   off += 16;

    k_place <<<NPB + 1, 1024, 0, stream>>>(ei, ew, W1, b1, W2, b2, cnt, rec, W12, cvec);
    k_z     <<<NZB, 256, 0, stream>>>(x, W12, z);
    k_deg   <<<NB, 256, 0, stream>>>(rec, cnt, z, dinv, zn);
    k_gather<<<NB, 256, 0, stream>>>(rec, cnt, dinv, zn, cvec, out);
}

// Round 11
// 76.431 us; speedup vs baseline: 1.3328x; 1.0291x over previous
//
#include <hip/hip_runtime.h>

#define N_NODES 100000
#define N_EDGES 1600000
#define HIDDEN 256

#define BSH 7                    // bucket = dst >> 7
#define BNODES 128               // nodes per bucket
#define NB 782                   // ceil(100000 / 128)
#define NPB 256                  // place blocks == sub-chunks per bucket == consumer block size
#define EPB 6250                 // edges per place block (256*6250 = 1.6M exact)
#define SLOTS 32                 // slots per (bucket, pblock): mean 8, P(ovf)~4e-13/pair
#define NZB 12500                // z blocks: 4 waves x 2 nodes = 8 nodes/block, exact cover

// rec layout: [bucket][pblock][slot], 8B records {src(17b) | dstloc(7b)<<17, w}
// cnt layout: [bucket][pblock]  -> consumers read coalesced; fully overwritten each call

// ---- K1: place (blocks 0..255) + W12/cvec fold (block 256) ----
__global__ __launch_bounds__(1024) void k_place(
        const int* __restrict__ ei, const float* __restrict__ ew,
        const float* __restrict__ W1, const float* __restrict__ b1,
        const float* __restrict__ W2, const float* __restrict__ b2,
        int* __restrict__ cnt, uint2* __restrict__ rec,
        float* __restrict__ W12, float* __restrict__ cvec) {
    const int tid = threadIdx.x, bid = blockIdx.x;
    if (bid == NPB) {                                 // ---- fold block ----
        if (tid < HIDDEN) {
            const float4* w1r = (const float4*)(W1 + (size_t)tid * 128);
            float a0 = 0.f, a1 = 0.f;
#pragma unroll 8
            for (int k4 = 0; k4 < 32; ++k4) {
                float4 v = w1r[k4];
                a0 += v.x * W2[8 * k4 + 0]; a1 += v.x * W2[8 * k4 + 1];
                a0 += v.y * W2[8 * k4 + 2]; a1 += v.y * W2[8 * k4 + 3];
                a0 += v.z * W2[8 * k4 + 4]; a1 += v.z * W2[8 * k4 + 5];
                a0 += v.w * W2[8 * k4 + 6]; a1 += v.w * W2[8 * k4 + 7];
            }
            W12[2 * tid] = a0; W12[2 * tid + 1] = a1;
            if (tid < 2) {
                float acc = b2[tid];
                for (int k = 0; k < 128; ++k) acc += b1[k] * W2[2 * k + tid];
                cvec[tid] = acc;
            }
        }
        return;
    }
    __shared__ int cursor[NB];
    for (int i = tid; i < NB; i += 1024) cursor[i] = 0;
    __syncthreads();
    const int e0 = bid * EPB, e1 = e0 + EPB;
    for (int e = e0 + tid; e < e1; e += 1024) {
        int d = ei[N_EDGES + e];
        int s = ei[e];
        float wv = ew[e];
        int bk = ((unsigned)d) >> BSH;
        int pos = atomicAdd(&cursor[bk], 1);          // block-local LDS cursor
        if (pos < SLOTS)                              // ~4e-13 per pair
            rec[((size_t)bk * NPB + bid) * SLOTS + pos] =
                make_uint2((unsigned)s | ((unsigned)(d & (BNODES - 1)) << 17),
                           __float_as_uint(wv));
    }
    __syncthreads();
    for (int i = tid; i < NB; i += 1024)
        cnt[(size_t)i * NPB + bid] = min(cursor[i], SLOTS);   // covers ALL entries
}

// ---- K2: blocks 0..NB-1: deg -> dinv.  blocks NB..NB+NZB-1: z = x@W12 (ILP-2).
//      The two halves are data-independent; deg rides under z's memory stream. ----
__global__ __launch_bounds__(256) void k_zdeg(
        const float* __restrict__ x, const float* __restrict__ W12,
        const uint2* __restrict__ rec, const int* __restrict__ cnt,
        float* __restrict__ z, float* __restrict__ dinv) {
    __shared__ float acc[BNODES];
    const int tid = threadIdx.x, bid = blockIdx.x;
    if (bid < NB) {
        // ---------- deg for bucket bid, one thread per sub-chunk ----------
        if (tid < BNODES) acc[tid] = 1.0f;            // self-loop w=1
        __syncthreads();
        const int n = cnt[(size_t)bid * NPB + tid];   // coalesced
        const uint2* r = rec + ((size_t)bid * NPB + tid) * SLOTS;
        for (int i = 0; i < n; ++i) {                 // ~8 iters, own 64B lines
            uint2 q = r[i];
            atomicAdd(&acc[q.x >> 17], __uint_as_float(q.y));
        }
        __syncthreads();
        if (tid < BNODES) {
            int node = bid * BNODES + tid;
            if (node < N_NODES) dinv[node] = rsqrtf(acc[tid]);  // deg >= 1
        }
    } else {
        // ---------- z: 2 nodes per wave, independent reduce chains ----------
        const int lane = tid & 63;
        const float2 w0 = ((const float2*)W12)[lane * 4 + 0];
        const float2 w1 = ((const float2*)W12)[lane * 4 + 1];
        const float2 w2 = ((const float2*)W12)[lane * 4 + 2];
        const float2 w3 = ((const float2*)W12)[lane * 4 + 3];
        const int n0 = (((bid - NB) * 4) + (tid >> 6)) * 2;
        const float4 xa = *(const float4*)(x + (size_t)n0 * HIDDEN + lane * 4);
        const float4 xb = *(const float4*)(x + (size_t)(n0 + 1) * HIDDEN + lane * 4);
        float a0 = xa.x * w0.x + xa.y * w1.x + xa.z * w2.x + xa.w * w3.x;
        float a1 = xa.x * w0.y + xa.y * w1.y + xa.z * w2.y + xa.w * w3.y;
        float c0 = xb.x * w0.x + xb.y * w1.x + xb.z * w2.x + xb.w * w3.x;
        float c1 = xb.x * w0.y + xb.y * w1.y + xb.z * w2.y + xb.w * w3.y;
#pragma unroll
        for (int m = 32; m >= 1; m >>= 1) {
            a0 += __shfl_xor(a0, m, 64);
            a1 += __shfl_xor(a1, m, 64);
            c0 += __shfl_xor(c0, m, 64);
            c1 += __shfl_xor(c1, m, 64);
        }
        if (lane == 0) *(float4*)(z + 2 * n0) = make_float4(a0, a1, c0, c1);
    }
}

// ---- K3: gather, one thread per sub-chunk; per record gather dinv[src], z[src];
//          flush fuses self-loop + bias ----
__global__ __launch_bounds__(256) void k_gather(
        const uint2* __restrict__ rec, const int* __restrict__ cnt,
        const float* __restrict__ dinv, const float* __restrict__ z,
        const float* __restrict__ cvec, float2* __restrict__ out) {
    __shared__ float ax[BNODES], ay[BNODES];
    const int tid = threadIdx.x, b = blockIdx.x;
    if (tid < BNODES) { ax[tid] = 0.f; ay[tid] = 0.f; }
    __syncthreads();
    const int n = cnt[(size_t)b * NPB + tid];             // coalesced
    const uint2* r = rec + ((size_t)b * NPB + tid) * SLOTS;
    for (int i = 0; i < n; ++i) {
        uint2 q = r[i];
        int s = (int)(q.x & 0x1FFFFu);
        float nw = dinv[s] * __uint_as_float(q.y);        // 4B gather (L2)
        float2 zv = ((const float2*)z)[s];                // 8B gather (L2)
        int dl = (int)(q.x >> 17);
        atomicAdd(&ax[dl], nw * zv.x);
        atomicAdd(&ay[dl], nw * zv.y);
    }
    __syncthreads();
    if (tid < BNODES) {
        int node = b * BNODES + tid;
        if (node < N_NODES) {
            float di = dinv[node];
            float2 zv = ((const float2*)z)[node];
            out[node] = make_float2(di * ax[tid] + di * di * zv.x + cvec[0],
                                    di * ay[tid] + di * di * zv.y + cvec[1]);
        }
    }
}

extern "C" void kernel_launch(void* const* d_in, const int* in_sizes, int n_in,
                              void* d_out, int out_size, void* d_ws, size_t ws_size,
                              hipStream_t stream) {
    const float* x  = (const float*)d_in[0];
    const int*   ei = (const int*)d_in[1];
    const float* ew = (const float*)d_in[2];
    const float* W1 = (const float*)d_in[3];
    const float* b1 = (const float*)d_in[4];
    const float* W2 = (const float*)d_in[5];
    const float* b2 = (const float*)d_in[6];
    float2* out = (float2*)d_out;

    char* ws = (char*)d_ws;
    uint2*  rec  = (uint2*)ws;           size_t off = (size_t)NB * NPB * SLOTS * 8;  // 51,249,152
    int*    cnt  = (int*)(ws + off);     off += (size_t)NB * NPB * 4;                // 800,768
    float*  dinv = (float*)(ws + off);   off += (size_t)N_NODES * 4;
    float*  z    = (float*)(ws + off);   off += (size_t)N_NODES * 8;
    float*  W12  = (float*)(ws + off);   off += HIDDEN * 2 * 4;
    float*  cvec = (float*)(ws + off);   off += 16;

    k_place <<<NPB + 1, 1024, 0, stream>>>(ei, ew, W1, b1, W2, b2, cnt, rec, W12, cvec);
    k_zdeg  <<<NB + NZB, 256, 0, stream>>>(x, W12, rec, cnt, z, dinv);
    k_gather<<<NB, 256, 0, stream>>>(rec, cnt, dinv, z, cvec, out);
}